// Round 6
// baseline (113.669 us; speedup 1.0000x reference)
//
#include <hip/hip_runtime.h>

#define NN 2048
#define NT 256          // threads per block (4 waves)
#define NB 4
#define NC 16
#define NCLS (NB * NC)
#define TILE 64
#define NTILES (NN / TILE)
#define KKEEP 176       // >= (K-1) + 64 = 163

typedef unsigned long long u64;

// orderable(score): ascending u32 == descending score
__device__ __forceinline__ unsigned score_hi(float s) {
  unsigned u = __float_as_uint(s);
  u ^= (u >> 31) ? 0xFFFFFFFFu : 0x80000000u;  // ascending-orderable
  return ~u;                                   // descending score
}
__device__ __forceinline__ u64 make_key(float s, int idx) {
  return ((u64)score_hi(s) << 32) | (unsigned)idx;
}

// IoU with the exact op order of the reference; asm guard blocks
// ffp-contract from fusing (ka + a - iw*ih) into an FMA.
__device__ __forceinline__ float iou_f(float kx1, float ky1, float kx2, float ky2, float ka,
                                       float x1, float y1, float x2, float y2, float a) {
  float ix1 = fmaxf(kx1, x1);
  float iy1 = fmaxf(ky1, y1);
  float ix2 = fminf(kx2, x2);
  float iy2 = fminf(ky2, y2);
  float iw = fmaxf(ix2 - ix1, 0.0f);
  float ih = fmaxf(iy2 - iy1, 0.0f);
  float inter = iw * ih;
  asm volatile("" : "+v"(inter));
  float denom = ka + a - inter;
  return inter / denom;
}

// ---------------- kernel 1: rank sort via register readlane broadcast ----------
// 256 blocks = 64 classes x 4 quarters; each thread ranks 2 elements.
// Keys live in 32 VGPRs per thread (reg r, lane l <-> element r*64+l);
// broadcast feed = one v_readlane (VALU, per-SIMD parallel), low word of the
// key is wave-uniform SALU. No LDS, no SMEM in the hot loop.
__global__ __launch_bounds__(NT) void rank_kernel(
    const float* __restrict__ scores,
    const float* __restrict__ boxes,
    float* __restrict__ wx1, float* __restrict__ wy1,
    float* __restrict__ wx2, float* __restrict__ wy2,
    float* __restrict__ wsc, int* __restrict__ widx)
{
  const int blk = blockIdx.x;
  const int bc  = blk >> 2;        // class id 0..63
  const int q   = blk & 3;         // quarter
  const int b   = bc >> 4;         // batch
  const int t   = threadIdx.x;
  const int ln  = t & 63;

  const float* __restrict__ scls = scores + (size_t)bc * NN;

  // stage all 2048 class keys' high words into 32 VGPRs (coalesced loads)
  unsigned hi[32];
#pragma unroll
  for (int r = 0; r < 32; r++) hi[r] = score_hi(scls[r * 64 + ln]);

  // my two elements
  const int i0 = q * 512 + t;
  const int i1 = i0 + 256;
  const float sc0 = scls[i0];
  const float sc1 = scls[i1];
  const u64 my0 = make_key(sc0, i0);
  const u64 my1 = make_key(sc1, i1);

  // rank = # keys strictly less than mine (keys unique via idx; self compares equal)
  int ra0 = 0, rb0 = 0, ra1 = 0, rb1 = 0;
#pragma unroll
  for (int r = 0; r < 32; r++) {
#pragma unroll 8
    for (int l = 0; l < 64; l++) {
      unsigned khi;
      asm("v_readlane_b32 %0, %1, %2" : "=s"(khi) : "v"(hi[r]), "s"(l));
      u64 kj = ((u64)khi << 32) | (unsigned)(r * 64 + l);
      if (l & 1) { rb0 += (kj < my0) ? 1 : 0; rb1 += (kj < my1) ? 1 : 0; }
      else       { ra0 += (kj < my0) ? 1 : 0; ra1 += (kj < my1) ? 1 : 0; }
    }
  }
  const int rank0 = ra0 + rb0;
  const int rank1 = ra1 + rb1;

  // gather boxes, fix min/max, scatter to sorted positions
  const float* __restrict__ bbase = boxes + (size_t)b * NN * 4;
  const size_t obase = (size_t)bc * NN;
  {
    float4 v = *(const float4*)(bbase + (size_t)i0 * 4);
    float x1 = fminf(v.x, v.z), x2 = fmaxf(v.x, v.z);
    float y1 = fminf(v.y, v.w), y2 = fmaxf(v.y, v.w);
    const size_t o = obase + rank0;
    wx1[o] = x1; wy1[o] = y1; wx2[o] = x2; wy2[o] = y2;
    wsc[o] = sc0; widx[o] = i0;
  }
  {
    float4 v = *(const float4*)(bbase + (size_t)i1 * 4);
    float x1 = fminf(v.x, v.z), x2 = fmaxf(v.x, v.z);
    float y1 = fminf(v.y, v.w), y2 = fmaxf(v.y, v.w);
    const size_t o = obase + rank1;
    wx1[o] = x1; wy1[o] = y1; wx2[o] = x2; wy2[o] = y2;
    wsc[o] = sc1; widx[o] = i1;
  }
}

// ---------------- kernel 2: per-class tiled greedy NMS ----------------
__global__ __launch_bounds__(NT) void greedy_kernel(
    const float* __restrict__ wx1, const float* __restrict__ wy1,
    const float* __restrict__ wx2, const float* __restrict__ wy2,
    const float* __restrict__ wsc, const int* __restrict__ widx,
    const float* __restrict__ iou_thr_p, const float* __restrict__ score_thr_p,
    int K, int* __restrict__ out)
{
  __shared__ float s_kx1[KKEEP], s_ky1[KKEEP], s_kx2[KKEEP], s_ky2[KKEEP], s_ka[KKEEP];
  __shared__ float s_tx1[TILE], s_ty1[TILE], s_tx2[TILE], s_ty2[TILE], s_ts[TILE];
  __shared__ int   s_tidx[TILE];
  __shared__ u64   s_colmask[4][TILE];
  __shared__ u64   s_dead[4];
  __shared__ int   s_total;

  const int bc = blockIdx.x;
  const int b  = bc >> 4;
  const int c  = bc & 15;
  const int t  = threadIdx.x;
  const int wv = t >> 6;
  const int ln = t & 63;

  const float iou_thr = *iou_thr_p;
  const float sthr    = *score_thr_p;

  int* orow = out + (size_t)bc * K * 3;
  for (int i = t; i < K * 3; i += NT) orow[i] = -1;
  if (t == 0) s_total = 0;

  const size_t base0 = (size_t)bc * NN;
  __syncthreads();

  for (int tile = 0; tile < NTILES; tile++) {
    const int base = tile * TILE;

    // load tile data into LDS (each wave loads distinct arrays)
    if      (wv == 0) { s_tx1[ln] = wx1[base0 + base + ln]; s_ts[ln]   = wsc[base0 + base + ln]; }
    else if (wv == 1) { s_ty1[ln] = wy1[base0 + base + ln]; s_tidx[ln] = widx[base0 + base + ln]; }
    else if (wv == 2) { s_tx2[ln] = wx2[base0 + base + ln]; }
    else              { s_ty2[ln] = wy2[base0 + base + ln]; }
    const int kcount = s_total;       // stable: last written before previous barrier
    __syncthreads();

    // Phase B: column ln owned per-wave; intra-tile triangle rows wv*16..+15
    // plus suppression vs kept list (strided by wave).
    float jx1 = s_tx1[ln], jy1 = s_ty1[ln], jx2 = s_tx2[ln], jy2 = s_ty2[ln];
    float ja  = (jx2 - jx1) * (jy2 - jy1);   // bit-identical to reference area
    u64 m = 0ULL;
    for (int r = 0; r < 16; r++) {
      int il = wv * 16 + r;
      if (il < ln) {
        float rx1 = s_tx1[il], ry1 = s_ty1[il], rx2 = s_tx2[il], ry2 = s_ty2[il];
        float ra  = (rx2 - rx1) * (ry2 - ry1);
        float iou = iou_f(rx1, ry1, rx2, ry2, ra, jx1, jy1, jx2, jy2, ja);
        if (iou > iou_thr) m |= (1ULL << il);
      }
    }
    s_colmask[wv][ln] = m;

    bool dead = false;
    for (int ki = wv; ki < kcount; ki += 4) {
      float iou = iou_f(s_kx1[ki], s_ky1[ki], s_kx2[ki], s_ky2[ki], s_ka[ki],
                        jx1, jy1, jx2, jy2, ja);
      if (iou > iou_thr) { dead = true; break; }
    }
    s_dead[wv] = __ballot(dead);
    __syncthreads();

    // Phase C: wave 0 resolves intra-tile greedy, appends kept, writes output
    if (t < 64) {
      u64 mc = s_colmask[0][ln] | s_colmask[1][ln] | s_colmask[2][ln] | s_colmask[3][ln];
      u64 alive = ~(s_dead[0] | s_dead[1] | s_dead[2] | s_dead[3]);
      for (int i = 0; i < TILE; i++) {
        if ((alive >> i) & 1ULL) {
          u64 kill = __ballot((int)((mc >> i) & 1ULL));
          alive &= ~kill;
        }
      }
      int total0 = s_total;
      bool kept = (alive >> ln) & 1ULL;
      int pos = __popcll(alive & ((1ULL << ln) - 1ULL));
      if (kept) {
        int kpos = total0 + pos;                 // <= 99 + 63 < KKEEP
        s_kx1[kpos] = jx1; s_ky1[kpos] = jy1;
        s_kx2[kpos] = jx2; s_ky2[kpos] = jy2; s_ka[kpos] = ja;
        if (kpos < K && s_ts[ln] >= sthr) {
          orow[kpos * 3 + 0] = b;
          orow[kpos * 3 + 1] = c;
          orow[kpos * 3 + 2] = s_tidx[ln];
        }
      }
      if (ln == 0) s_total = total0 + (int)__popcll(alive);
    }
    __syncthreads();
    if (s_total >= K) break;   // uniform; stable until next Phase C
  }
}

extern "C" void kernel_launch(void* const* d_in, const int* in_sizes, int n_in,
                              void* d_out, int out_size, void* d_ws, size_t ws_size,
                              hipStream_t stream) {
  const float* boxes  = (const float*)d_in[0];
  const float* scores = (const float*)d_in[1];
  const float* iou_p  = (const float*)d_in[3];
  const float* sth_p  = (const float*)d_in[4];
  int* out = (int*)d_out;

  const int K = out_size / (NCLS * 3);
  const size_t plane = (size_t)NCLS * NN;

  float* w   = (float*)d_ws;
  float* wx1 = w + 0 * plane;
  float* wy1 = w + 1 * plane;
  float* wx2 = w + 2 * plane;
  float* wy2 = w + 3 * plane;
  float* wsc = w + 4 * plane;
  int*  widx = (int*)(w + 5 * plane);

  hipLaunchKernelGGL(rank_kernel, dim3(NCLS * 4), dim3(NT), 0, stream,
                     scores, boxes, wx1, wy1, wx2, wy2, wsc, widx);
  hipLaunchKernelGGL(greedy_kernel, dim3(NCLS), dim3(NT), 0, stream,
                     wx1, wy1, wx2, wy2, wsc, widx, iou_p, sth_p, K, out);
}

// Round 7
// 102.978 us; speedup vs baseline: 1.1038x; 1.1038x over previous
//
#include <hip/hip_runtime.h>

#define NN 2048
#define NT 256          // threads per block (4 waves)
#define NB 4
#define NC 16
#define NCLS (NB * NC)
#define TILE 64
#define NTILES (NN / TILE)
#define KKEEP 176       // >= (K-1) + 64 = 163

typedef unsigned long long u64;

// orderable(score): ascending u32 == descending score
__device__ __forceinline__ unsigned score_hi(float s) {
  unsigned u = __float_as_uint(s);
  u ^= (u >> 31) ? 0xFFFFFFFFu : 0x80000000u;  // ascending-orderable
  return ~u;                                   // descending score
}
__device__ __forceinline__ float hi_score(unsigned hiw) {
  unsigned u = ~hiw;
  unsigned bits = (u >> 31) ? (u ^ 0x80000000u) : ~u;
  return __uint_as_float(bits);
}

// IoU with the exact op order of the reference; asm guard blocks
// ffp-contract from fusing (ka + a - iw*ih) into an FMA.
__device__ __forceinline__ float iou_f(float kx1, float ky1, float kx2, float ky2, float ka,
                                       float x1, float y1, float x2, float y2, float a) {
  float ix1 = fmaxf(kx1, x1);
  float iy1 = fmaxf(ky1, y1);
  float ix2 = fminf(kx2, x2);
  float iy2 = fminf(ky2, y2);
  float iw = fmaxf(ix2 - ix1, 0.0f);
  float ih = fmaxf(iy2 - iy1, 0.0f);
  float inter = iw * ih;
  asm volatile("" : "+v"(inter));
  float denom = ka + a - inter;
  return inter / denom;
}

// ---------------- kernel 1: rank sort, rolled readlane broadcast ----------
// 256 blocks = 64 classes x 4 quarters; each thread ranks 2 elements.
// All 2048 class keys' high words live in 32 VGPRs per wave (reg r, lane l
// <-> element r*64+l). Feed = v_readlane (VALU, per-SIMD parallel; no LDS
// pipe, no SMEM). Outer l-loop stays ROLLED (64 iters, ~1.5KB body) so the
// code fits I$ -- the round-6 full unroll was I$-fetch-bound.
__global__ __launch_bounds__(NT) void rank_kernel(
    const float* __restrict__ scores,
    const float* __restrict__ boxes,
    float* __restrict__ wx1, float* __restrict__ wy1,
    float* __restrict__ wx2, float* __restrict__ wy2,
    float* __restrict__ wsc, int* __restrict__ widx)
{
  const int blk = blockIdx.x;
  const int bc  = blk >> 2;        // class id 0..63
  const int q   = blk & 3;         // quarter
  const int b   = bc >> 4;         // batch
  const int t   = threadIdx.x;
  const int wv  = t >> 6;
  const int ln  = t & 63;

  const float* __restrict__ scls = scores + (size_t)bc * NN;

  // stage all 2048 class keys' high words into 32 VGPRs (coalesced loads)
  unsigned hi[32];
#pragma unroll
  for (int r = 0; r < 32; r++) hi[r] = score_hi(scls[r * 64 + ln]);

  // my two elements: i0 = q*512 + wv*64 + ln  ->  staged at reg q*8+wv, own lane
  const int i0 = q * 512 + t;
  const int i1 = i0 + 256;
  const unsigned myhi0 = hi[q * 8 + wv];
  const unsigned myhi1 = hi[q * 8 + wv + 4];
  const u64 my0 = ((u64)myhi0 << 32) | (unsigned)i0;
  const u64 my1 = ((u64)myhi1 << 32) | (unsigned)i1;

  // rank = # keys strictly less than mine (u64 total order; keys unique)
  int c0a = 0, c0b = 0, c1a = 0, c1b = 0;
#pragma unroll 1
  for (int l = 0; l < 64; l++) {
#pragma unroll
    for (int r = 0; r < 32; r++) {
      unsigned khi = __builtin_amdgcn_readlane(hi[r], l);
      u64 kj = ((u64)khi << 32) | (unsigned)(r * 64 + l);
      if (r & 1) { c0b += (kj < my0) ? 1 : 0; c1b += (kj < my1) ? 1 : 0; }
      else       { c0a += (kj < my0) ? 1 : 0; c1a += (kj < my1) ? 1 : 0; }
    }
  }
  const int rank0 = c0a + c0b;
  const int rank1 = c1a + c1b;

  // gather boxes, fix min/max, scatter to sorted positions
  const float* __restrict__ bbase = boxes + (size_t)b * NN * 4;
  const size_t obase = (size_t)bc * NN;
  {
    float4 v = *(const float4*)(bbase + (size_t)i0 * 4);
    float x1 = fminf(v.x, v.z), x2 = fmaxf(v.x, v.z);
    float y1 = fminf(v.y, v.w), y2 = fmaxf(v.y, v.w);
    const size_t o = obase + rank0;
    wx1[o] = x1; wy1[o] = y1; wx2[o] = x2; wy2[o] = y2;
    wsc[o] = hi_score(myhi0); widx[o] = i0;
  }
  {
    float4 v = *(const float4*)(bbase + (size_t)i1 * 4);
    float x1 = fminf(v.x, v.z), x2 = fmaxf(v.x, v.z);
    float y1 = fminf(v.y, v.w), y2 = fmaxf(v.y, v.w);
    const size_t o = obase + rank1;
    wx1[o] = x1; wy1[o] = y1; wx2[o] = x2; wy2[o] = y2;
    wsc[o] = hi_score(myhi1); widx[o] = i1;
  }
}

// ---------------- kernel 2: per-class tiled greedy NMS ----------------
__global__ __launch_bounds__(NT) void greedy_kernel(
    const float* __restrict__ wx1, const float* __restrict__ wy1,
    const float* __restrict__ wx2, const float* __restrict__ wy2,
    const float* __restrict__ wsc, const int* __restrict__ widx,
    const float* __restrict__ iou_thr_p, const float* __restrict__ score_thr_p,
    int K, int* __restrict__ out)
{
  __shared__ float s_kx1[KKEEP], s_ky1[KKEEP], s_kx2[KKEEP], s_ky2[KKEEP], s_ka[KKEEP];
  __shared__ float s_tx1[TILE], s_ty1[TILE], s_tx2[TILE], s_ty2[TILE], s_ts[TILE];
  __shared__ int   s_tidx[TILE];
  __shared__ u64   s_colmask[4][TILE];
  __shared__ u64   s_dead[4];
  __shared__ int   s_total;

  const int bc = blockIdx.x;
  const int b  = bc >> 4;
  const int c  = bc & 15;
  const int t  = threadIdx.x;
  const int wv = t >> 6;
  const int ln = t & 63;

  const float iou_thr = *iou_thr_p;
  const float sthr    = *score_thr_p;

  int* orow = out + (size_t)bc * K * 3;
  for (int i = t; i < K * 3; i += NT) orow[i] = -1;
  if (t == 0) s_total = 0;

  const size_t base0 = (size_t)bc * NN;
  __syncthreads();

  for (int tile = 0; tile < NTILES; tile++) {
    const int base = tile * TILE;

    // load tile data into LDS (each wave loads distinct arrays)
    if      (wv == 0) { s_tx1[ln] = wx1[base0 + base + ln]; s_ts[ln]   = wsc[base0 + base + ln]; }
    else if (wv == 1) { s_ty1[ln] = wy1[base0 + base + ln]; s_tidx[ln] = widx[base0 + base + ln]; }
    else if (wv == 2) { s_tx2[ln] = wx2[base0 + base + ln]; }
    else              { s_ty2[ln] = wy2[base0 + base + ln]; }
    const int kcount = s_total;       // stable: last written before previous barrier
    __syncthreads();

    // Phase B: column ln owned per-wave; intra-tile triangle rows wv*16..+15
    // plus suppression vs kept list (strided by wave).
    float jx1 = s_tx1[ln], jy1 = s_ty1[ln], jx2 = s_tx2[ln], jy2 = s_ty2[ln];
    float ja  = (jx2 - jx1) * (jy2 - jy1);   // bit-identical to reference area
    u64 m = 0ULL;
    for (int r = 0; r < 16; r++) {
      int il = wv * 16 + r;
      if (il < ln) {
        float rx1 = s_tx1[il], ry1 = s_ty1[il], rx2 = s_tx2[il], ry2 = s_ty2[il];
        float ra  = (rx2 - rx1) * (ry2 - ry1);
        float iou = iou_f(rx1, ry1, rx2, ry2, ra, jx1, jy1, jx2, jy2, ja);
        if (iou > iou_thr) m |= (1ULL << il);
      }
    }
    s_colmask[wv][ln] = m;

    bool dead = false;
    for (int ki = wv; ki < kcount; ki += 4) {
      float iou = iou_f(s_kx1[ki], s_ky1[ki], s_kx2[ki], s_ky2[ki], s_ka[ki],
                        jx1, jy1, jx2, jy2, ja);
      if (iou > iou_thr) { dead = true; break; }
    }
    s_dead[wv] = __ballot(dead);
    __syncthreads();

    // Phase C: wave 0 resolves intra-tile greedy, appends kept, writes output
    if (t < 64) {
      u64 mc = s_colmask[0][ln] | s_colmask[1][ln] | s_colmask[2][ln] | s_colmask[3][ln];
      u64 alive = ~(s_dead[0] | s_dead[1] | s_dead[2] | s_dead[3]);
      for (int i = 0; i < TILE; i++) {
        if ((alive >> i) & 1ULL) {
          u64 kill = __ballot((int)((mc >> i) & 1ULL));
          alive &= ~kill;
        }
      }
      int total0 = s_total;
      bool kept = (alive >> ln) & 1ULL;
      int pos = __popcll(alive & ((1ULL << ln) - 1ULL));
      if (kept) {
        int kpos = total0 + pos;                 // <= 99 + 63 < KKEEP
        s_kx1[kpos] = jx1; s_ky1[kpos] = jy1;
        s_kx2[kpos] = jx2; s_ky2[kpos] = jy2; s_ka[kpos] = ja;
        if (kpos < K && s_ts[ln] >= sthr) {
          orow[kpos * 3 + 0] = b;
          orow[kpos * 3 + 1] = c;
          orow[kpos * 3 + 2] = s_tidx[ln];
        }
      }
      if (ln == 0) s_total = total0 + (int)__popcll(alive);
    }
    __syncthreads();
    if (s_total >= K) break;   // uniform; stable until next Phase C
  }
}

extern "C" void kernel_launch(void* const* d_in, const int* in_sizes, int n_in,
                              void* d_out, int out_size, void* d_ws, size_t ws_size,
                              hipStream_t stream) {
  const float* boxes  = (const float*)d_in[0];
  const float* scores = (const float*)d_in[1];
  const float* iou_p  = (const float*)d_in[3];
  const float* sth_p  = (const float*)d_in[4];
  int* out = (int*)d_out;

  const int K = out_size / (NCLS * 3);
  const size_t plane = (size_t)NCLS * NN;

  float* w   = (float*)d_ws;
  float* wx1 = w + 0 * plane;
  float* wy1 = w + 1 * plane;
  float* wx2 = w + 2 * plane;
  float* wy2 = w + 3 * plane;
  float* wsc = w + 4 * plane;
  int*  widx = (int*)(w + 5 * plane);

  hipLaunchKernelGGL(rank_kernel, dim3(NCLS * 4), dim3(NT), 0, stream,
                     scores, boxes, wx1, wy1, wx2, wy2, wsc, widx);
  hipLaunchKernelGGL(greedy_kernel, dim3(NCLS), dim3(NT), 0, stream,
                     wx1, wy1, wx2, wy2, wsc, widx, iou_p, sth_p, K, out);
}

// Round 8
// 67.112 us; speedup vs baseline: 1.6937x; 1.5344x over previous
//
#include <hip/hip_runtime.h>

#define NN 2048
#define NT 256          // threads per block (4 waves)
#define NB 4
#define NC 16
#define NCLS (NB * NC)
#define TILE 64
#define NTILES (NN / TILE)
#define KKEEP 176       // >= (K-1) + 64 = 163

typedef unsigned long long u64;

// orderable(score): ascending u32 == descending score
__device__ __forceinline__ unsigned score_hi(float s) {
  unsigned u = __float_as_uint(s);
  u ^= (u >> 31) ? 0xFFFFFFFFu : 0x80000000u;  // ascending-orderable
  return ~u;                                   // descending score
}
__device__ __forceinline__ float hi_score(unsigned hiw) {
  unsigned u = ~hiw;
  unsigned bits = (u >> 31) ? (u ^ 0x80000000u) : ~u;
  return __uint_as_float(bits);
}

// IoU with the exact op order of the reference; asm guard blocks
// ffp-contract from fusing (ka + a - iw*ih) into an FMA.
__device__ __forceinline__ float iou_f(float kx1, float ky1, float kx2, float ky2, float ka,
                                       float x1, float y1, float x2, float y2, float a) {
  float ix1 = fmaxf(kx1, x1);
  float iy1 = fmaxf(ky1, y1);
  float ix2 = fminf(kx2, x2);
  float iy2 = fminf(ky2, y2);
  float iw = fmaxf(ix2 - ix1, 0.0f);
  float ih = fmaxf(iy2 - iy1, 0.0f);
  float inter = iw * ih;
  asm volatile("" : "+v"(inter));
  float denom = ka + a - inter;
  return inter / denom;
}

// ---------------- kernel 1: rank sort via LDS b128 broadcast ----------------
// 256 blocks = 64 classes x 4 quarters; each thread ranks 2 elements.
// Keys = u32 orderable hi-words in LDS (8 KB); delivery = ds_read_b128
// broadcast: 4 keys per ~12-cycle LDS op (3 cyc/key, vs 5.7 for u64 b64).
// The u64 compare key's low word is the uniform loop index (built once per
// key, shared by both elements). Compares: v_cmp_lt_u64 + add, 2 VALU each.
__global__ __launch_bounds__(NT) void rank_kernel(
    const float* __restrict__ scores,
    const float* __restrict__ boxes,
    float* __restrict__ wx1, float* __restrict__ wy1,
    float* __restrict__ wx2, float* __restrict__ wy2,
    float* __restrict__ wsc, int* __restrict__ widx)
{
  __shared__ unsigned s_hi[NN];    // 8 KB

  const int blk = blockIdx.x;
  const int bc  = blk >> 2;        // class id 0..63
  const int q   = blk & 3;         // quarter
  const int b   = bc >> 4;         // batch
  const int t   = threadIdx.x;

  const float* __restrict__ scls = scores + (size_t)bc * NN;

  // stage orderable hi-words: 8 keys/thread via two float4 loads, b128 stores
  {
    const float4* s4 = (const float4*)scls;
    uint4* d4 = (uint4*)s_hi;
    float4 v = s4[t];
    d4[t] = make_uint4(score_hi(v.x), score_hi(v.y), score_hi(v.z), score_hi(v.w));
    v = s4[t + 256];
    d4[t + 256] = make_uint4(score_hi(v.x), score_hi(v.y), score_hi(v.z), score_hi(v.w));
  }
  __syncthreads();

  // my two elements
  const int i0 = q * 512 + t;
  const int i1 = i0 + 256;
  const unsigned h0 = s_hi[i0];    // per-lane stride-1 reads: conflict-free
  const unsigned h1 = s_hi[i1];
  const u64 my0 = ((u64)h0 << 32) | (unsigned)i0;
  const u64 my1 = ((u64)h1 << 32) | (unsigned)i1;

  // rank = # keys strictly less than mine (u64 total order; keys unique)
  int c0 = 0, c1 = 0, c2 = 0, c3 = 0;
  const uint4* k4 = (const uint4*)s_hi;
#pragma unroll 1
  for (int jc = 0; jc < NN / 8; jc++) {
    const uint4 ka = k4[jc * 2];       // uniform addr -> b128 broadcast
    const uint4 kb = k4[jc * 2 + 1];
    const int j = jc * 8;
    u64 kj;
    kj = ((u64)ka.x << 32) | (unsigned)(j + 0); c0 += (kj < my0); c1 += (kj < my1);
    kj = ((u64)ka.y << 32) | (unsigned)(j + 1); c2 += (kj < my0); c3 += (kj < my1);
    kj = ((u64)ka.z << 32) | (unsigned)(j + 2); c0 += (kj < my0); c1 += (kj < my1);
    kj = ((u64)ka.w << 32) | (unsigned)(j + 3); c2 += (kj < my0); c3 += (kj < my1);
    kj = ((u64)kb.x << 32) | (unsigned)(j + 4); c0 += (kj < my0); c1 += (kj < my1);
    kj = ((u64)kb.y << 32) | (unsigned)(j + 5); c2 += (kj < my0); c3 += (kj < my1);
    kj = ((u64)kb.z << 32) | (unsigned)(j + 6); c0 += (kj < my0); c1 += (kj < my1);
    kj = ((u64)kb.w << 32) | (unsigned)(j + 7); c2 += (kj < my0); c3 += (kj < my1);
  }
  const int rank0 = c0 + c2;
  const int rank1 = c1 + c3;

  // gather boxes, fix min/max, scatter to sorted positions
  const float* __restrict__ bbase = boxes + (size_t)b * NN * 4;
  const size_t obase = (size_t)bc * NN;
  {
    float4 v = *(const float4*)(bbase + (size_t)i0 * 4);
    float x1 = fminf(v.x, v.z), x2 = fmaxf(v.x, v.z);
    float y1 = fminf(v.y, v.w), y2 = fmaxf(v.y, v.w);
    const size_t o = obase + rank0;
    wx1[o] = x1; wy1[o] = y1; wx2[o] = x2; wy2[o] = y2;
    wsc[o] = hi_score(h0); widx[o] = i0;
  }
  {
    float4 v = *(const float4*)(bbase + (size_t)i1 * 4);
    float x1 = fminf(v.x, v.z), x2 = fmaxf(v.x, v.z);
    float y1 = fminf(v.y, v.w), y2 = fmaxf(v.y, v.w);
    const size_t o = obase + rank1;
    wx1[o] = x1; wy1[o] = y1; wx2[o] = x2; wy2[o] = y2;
    wsc[o] = hi_score(h1); widx[o] = i1;
  }
}

// ---------------- kernel 2: per-class tiled greedy NMS ----------------
__global__ __launch_bounds__(NT) void greedy_kernel(
    const float* __restrict__ wx1, const float* __restrict__ wy1,
    const float* __restrict__ wx2, const float* __restrict__ wy2,
    const float* __restrict__ wsc, const int* __restrict__ widx,
    const float* __restrict__ iou_thr_p, const float* __restrict__ score_thr_p,
    int K, int* __restrict__ out)
{
  __shared__ float s_kx1[KKEEP], s_ky1[KKEEP], s_kx2[KKEEP], s_ky2[KKEEP], s_ka[KKEEP];
  __shared__ float s_tx1[TILE], s_ty1[TILE], s_tx2[TILE], s_ty2[TILE], s_ts[TILE];
  __shared__ int   s_tidx[TILE];
  __shared__ u64   s_colmask[4][TILE];
  __shared__ u64   s_dead[4];
  __shared__ int   s_total;

  const int bc = blockIdx.x;
  const int b  = bc >> 4;
  const int c  = bc & 15;
  const int t  = threadIdx.x;
  const int wv = t >> 6;
  const int ln = t & 63;

  const float iou_thr = *iou_thr_p;
  const float sthr    = *score_thr_p;

  int* orow = out + (size_t)bc * K * 3;
  for (int i = t; i < K * 3; i += NT) orow[i] = -1;
  if (t == 0) s_total = 0;

  const size_t base0 = (size_t)bc * NN;
  __syncthreads();

  for (int tile = 0; tile < NTILES; tile++) {
    const int base = tile * TILE;

    // load tile data into LDS (each wave loads distinct arrays)
    if      (wv == 0) { s_tx1[ln] = wx1[base0 + base + ln]; s_ts[ln]   = wsc[base0 + base + ln]; }
    else if (wv == 1) { s_ty1[ln] = wy1[base0 + base + ln]; s_tidx[ln] = widx[base0 + base + ln]; }
    else if (wv == 2) { s_tx2[ln] = wx2[base0 + base + ln]; }
    else              { s_ty2[ln] = wy2[base0 + base + ln]; }
    const int kcount = s_total;       // stable: last written before previous barrier
    __syncthreads();

    // Phase B: column ln owned per-wave; intra-tile triangle rows wv*16..+15
    // plus suppression vs kept list (strided by wave).
    float jx1 = s_tx1[ln], jy1 = s_ty1[ln], jx2 = s_tx2[ln], jy2 = s_ty2[ln];
    float ja  = (jx2 - jx1) * (jy2 - jy1);   // bit-identical to reference area
    u64 m = 0ULL;
    for (int r = 0; r < 16; r++) {
      int il = wv * 16 + r;
      if (il < ln) {
        float rx1 = s_tx1[il], ry1 = s_ty1[il], rx2 = s_tx2[il], ry2 = s_ty2[il];
        float ra  = (rx2 - rx1) * (ry2 - ry1);
        float iou = iou_f(rx1, ry1, rx2, ry2, ra, jx1, jy1, jx2, jy2, ja);
        if (iou > iou_thr) m |= (1ULL << il);
      }
    }
    s_colmask[wv][ln] = m;

    bool dead = false;
    for (int ki = wv; ki < kcount; ki += 4) {
      float iou = iou_f(s_kx1[ki], s_ky1[ki], s_kx2[ki], s_ky2[ki], s_ka[ki],
                        jx1, jy1, jx2, jy2, ja);
      if (iou > iou_thr) { dead = true; break; }
    }
    s_dead[wv] = __ballot(dead);
    __syncthreads();

    // Phase C: wave 0 resolves intra-tile greedy, appends kept, writes output
    if (t < 64) {
      u64 mc = s_colmask[0][ln] | s_colmask[1][ln] | s_colmask[2][ln] | s_colmask[3][ln];
      u64 alive = ~(s_dead[0] | s_dead[1] | s_dead[2] | s_dead[3]);
      for (int i = 0; i < TILE; i++) {
        if ((alive >> i) & 1ULL) {
          u64 kill = __ballot((int)((mc >> i) & 1ULL));
          alive &= ~kill;
        }
      }
      int total0 = s_total;
      bool kept = (alive >> ln) & 1ULL;
      int pos = __popcll(alive & ((1ULL << ln) - 1ULL));
      if (kept) {
        int kpos = total0 + pos;                 // <= 99 + 63 < KKEEP
        s_kx1[kpos] = jx1; s_ky1[kpos] = jy1;
        s_kx2[kpos] = jx2; s_ky2[kpos] = jy2; s_ka[kpos] = ja;
        if (kpos < K && s_ts[ln] >= sthr) {
          orow[kpos * 3 + 0] = b;
          orow[kpos * 3 + 1] = c;
          orow[kpos * 3 + 2] = s_tidx[ln];
        }
      }
      if (ln == 0) s_total = total0 + (int)__popcll(alive);
    }
    __syncthreads();
    if (s_total >= K) break;   // uniform; stable until next Phase C
  }
}

extern "C" void kernel_launch(void* const* d_in, const int* in_sizes, int n_in,
                              void* d_out, int out_size, void* d_ws, size_t ws_size,
                              hipStream_t stream) {
  const float* boxes  = (const float*)d_in[0];
  const float* scores = (const float*)d_in[1];
  const float* iou_p  = (const float*)d_in[3];
  const float* sth_p  = (const float*)d_in[4];
  int* out = (int*)d_out;

  const int K = out_size / (NCLS * 3);
  const size_t plane = (size_t)NCLS * NN;

  float* w   = (float*)d_ws;
  float* wx1 = w + 0 * plane;
  float* wy1 = w + 1 * plane;
  float* wx2 = w + 2 * plane;
  float* wy2 = w + 3 * plane;
  float* wsc = w + 4 * plane;
  int*  widx = (int*)(w + 5 * plane);

  hipLaunchKernelGGL(rank_kernel, dim3(NCLS * 4), dim3(NT), 0, stream,
                     scores, boxes, wx1, wy1, wx2, wy2, wsc, widx);
  hipLaunchKernelGGL(greedy_kernel, dim3(NCLS), dim3(NT), 0, stream,
                     wx1, wy1, wx2, wy2, wsc, widx, iou_p, sth_p, K, out);
}